// Round 11
// baseline (149.460 us; speedup 1.0000x reference)
//
#include <hip/hip_runtime.h>
#include <stdint.h>

#define N_TOK 8192
#define D_DIM 1024
#define E_NUM 8

typedef float f32x4 __attribute__((ext_vector_type(4)));
typedef __bf16 bf16x8 __attribute__((ext_vector_type(8)));

__device__ __forceinline__ unsigned short f32_to_bf16_bits(float f) {
  union { float f; uint32_t u; } v; v.f = f;
  uint32_t u = v.u;
  uint32_t r = u + 0x7fffu + ((u >> 16) & 1u);  // RNE
  return (unsigned short)(r >> 16);
}

__device__ __forceinline__ void load_lds16(const void* g, void* l) {
  // async global->LDS, 16B/lane, dest = uniform base + lane*16
  __builtin_amdgcn_global_load_lds(
      (const __attribute__((address_space(1))) void*)g,
      (__attribute__((address_space(3))) void*)l, 16, 0, 0);
}

// ---------- shared 64x64 fp32->bf16 transpose tile (LDS-staged) ----------
__device__ __forceinline__ void transpose_tile(unsigned short (*T)[72],
                                               const float* __restrict__ S,
                                               unsigned short* __restrict__ O,
                                               int r0, int c0, int t) {
  const int rr = t >> 4;
  const int cc = (t & 15) * 4;
#pragma unroll
  for (int p = 0; p < 4; p++) {
    int r = p * 16 + rr;
    float4 v = *reinterpret_cast<const float4*>(S + (size_t)(r0 + r) * 1024 + c0 + cc);
    T[cc + 0][r] = f32_to_bf16_bits(v.x);
    T[cc + 1][r] = f32_to_bf16_bits(v.y);
    T[cc + 2][r] = f32_to_bf16_bits(v.z);
    T[cc + 3][r] = f32_to_bf16_bits(v.w);
  }
  __syncthreads();
#pragma unroll
  for (int p = 0; p < 4; p++) {
    int c = p * 16 + rr;
    ushort4 o = *reinterpret_cast<const ushort4*>(&T[c][cc]);
    *reinterpret_cast<ushort4*>(O + (size_t)(c0 + c) * 1024 + r0 + cc) = o;
  }
}

// ---------- Wp [1024][8] -> WpT [8][1024] ----------
__global__ __launch_bounds__(256) void wpt_kernel(const float* __restrict__ Wp,
                                                  float* __restrict__ WpT) {
  int i = blockIdx.x * 256 + threadIdx.x;  // 8192 total
  int e = i >> 10, d = i & 1023;
  WpT[i] = Wp[(size_t)d * E_NUM + e];
}

// ---------- fused: routing (fp64 logits) + x->bf16 + W1T + W2T ----------
// bids 0..2047 routing; 2048..4095 W1 transpose; 4096..6143 W2 transpose
// (overlap path only). fp64 logits so argmax matches the np reference.
// NO global atomics (R3: same-line atomicAdds serialized ~70us of tail).
__global__ __launch_bounds__(256) void routing_w1t_kernel(
    const float* __restrict__ x, const float* __restrict__ WpT,
    const float* __restrict__ bp, float* __restrict__ probs_out,
    float* __restrict__ chosenF, int* __restrict__ chosen,
    unsigned short* __restrict__ xb,
    const float* __restrict__ W1, unsigned short* __restrict__ W1t,
    const float* __restrict__ W2, unsigned short* __restrict__ W2t) {
  __shared__ __align__(16) unsigned short T[64][72];
  __shared__ __align__(16) float pbuf[4][8];
  if (blockIdx.x >= 4096) {  // W2 transpose role
    const int tb = blockIdx.x - 4096;
    const int e = tb >> 8, rc = tb & 255;
    transpose_tile(T, W2 + ((size_t)e << 20), W2t + ((size_t)e << 20),
                   (rc >> 4) * 64, (rc & 15) * 64, threadIdx.x);
    return;
  }
  if (blockIdx.x >= 2048) {  // W1 transpose role
    const int tb = blockIdx.x - 2048;
    const int e = tb >> 8, rc = tb & 255;
    transpose_tile(T, W1 + ((size_t)e << 20), W1t + ((size_t)e << 20),
                   (rc >> 4) * 64, (rc & 15) * 64, threadIdx.x);
    return;
  }
  const int wave = threadIdx.x >> 6;
  const int lane = threadIdx.x & 63;
  const int token = blockIdx.x * 4 + wave;
  const float* xr = x + (size_t)token * D_DIM;
  unsigned short* xbr = xb + (size_t)token * D_DIM;
  double acc[E_NUM];
#pragma unroll
  for (int e = 0; e < E_NUM; e++) acc[e] = 0.0;
#pragma unroll
  for (int it = 0; it < 4; it++) {
    const int d0 = it * 256 + lane * 4;
    float4 xv = *reinterpret_cast<const float4*>(xr + d0);
    ushort4 o;
    o.x = f32_to_bf16_bits(xv.x);
    o.y = f32_to_bf16_bits(xv.y);
    o.z = f32_to_bf16_bits(xv.z);
    o.w = f32_to_bf16_bits(xv.w);
    *reinterpret_cast<ushort4*>(xbr + d0) = o;
#pragma unroll
    for (int e = 0; e < E_NUM; e++) {
      float4 w = *reinterpret_cast<const float4*>(WpT + (e << 10) + d0);  // coalesced
      acc[e] += (double)xv.x * (double)w.x;
      acc[e] += (double)xv.y * (double)w.y;
      acc[e] += (double)xv.z * (double)w.z;
      acc[e] += (double)xv.w * (double)w.w;
    }
  }
#pragma unroll
  for (int e = 0; e < E_NUM; e++) {
#pragma unroll
    for (int off = 32; off > 0; off >>= 1) acc[e] += __shfl_xor(acc[e], off);
  }
  if (lane == 0) {
    double lg[E_NUM];
#pragma unroll
    for (int e = 0; e < E_NUM; e++) lg[e] = acc[e] + (double)bp[e];
    int best = 0;
    double bv = lg[0];
#pragma unroll
    for (int e = 1; e < E_NUM; e++)
      if (lg[e] > bv) { bv = lg[e]; best = e; }  // strict > == first-max (jnp.argmax)
    double s = 0.0, ex[E_NUM];
#pragma unroll
    for (int e = 0; e < E_NUM; e++) { ex[e] = exp(lg[e] - bv); s += ex[e]; }
    double inv = 1.0 / s;
#pragma unroll
    for (int e = 0; e < E_NUM; e++) pbuf[wave][e] = (float)(ex[e] * inv);
    chosenF[token] = (float)best;
    chosen[token] = best;
  }
  __syncthreads();
  if (threadIdx.x < 8) {  // coalesced 128B probs store per block
    float4 v = *reinterpret_cast<const float4*>(
        &pbuf[threadIdx.x >> 1][(threadIdx.x & 1) * 4]);
    reinterpret_cast<float4*>(probs_out + (size_t)blockIdx.x * 32)[threadIdx.x] = v;
  }
}

// ---------- scan + scatter, 8 blocks (one per expert), LDS atomics only ----------
__global__ __launch_bounds__(256) void scan_scatter_kernel(
    const int* __restrict__ chosen, int* __restrict__ offsets,
    int* __restrict__ perm) {
  __shared__ int hist[E_NUM];
  __shared__ int cur;
  const int e = blockIdx.x;
  const int t = threadIdx.x;
  if (t < E_NUM) hist[t] = 0;
  __syncthreads();
  for (int n = t; n < N_TOK; n += 256) atomicAdd(&hist[chosen[n]], 1);
  __syncthreads();
  if (t == 0) {
    int off = 0;
    for (int i = 0; i < e; i++) off += hist[i];
    cur = off;
    if (e == 0) {
      int o = 0;
      for (int i = 0; i < E_NUM; i++) { offsets[i] = o; o += hist[i]; }
      offsets[E_NUM] = o;
    }
  }
  __syncthreads();
  for (int n = t; n < N_TOK; n += 256) {
    if (chosen[n] == e) {
      int p = atomicAdd(&cur, 1);  // in-group order irrelevant
      perm[p] = n;
    }
  }
}

// ---------- standalone per-expert transpose (sequential fallback path) ----------
__global__ __launch_bounds__(256) void transpose_cast_kernel(
    const float* __restrict__ src, unsigned short* __restrict__ dst) {
  __shared__ __align__(16) unsigned short T[64][72];
  const int e = blockIdx.z;
  transpose_tile(T, src + ((size_t)e << 20), dst + ((size_t)e << 20),
                 blockIdx.y * 64, blockIdx.x * 64, threadIdx.x);
}

// ---------- R11 EXPERIMENT: deep-pipelined 256x128, 8 waves, 3 K-slots ----------
// R10 A/B refuted occupancy as the lever (41% occ = 50.6us vs 24% = 47us);
// all 2-phase variants plateau ~47us = m233's stage+drain+barrier overhead.
// This kernel tests DEPTH (the m201/m218 mechanism): 3 rotating BK=64 slots
// (144KB LDS, 1 block/CU), ONE s_barrier per K-step (all waves stay within
// the same body between barriers: readers use slot kt%3, stagers write slot
// (kt+2)%3 -- disjoint, so the trailing barrier is unnecessary), stage issued
// at body TOP (2 K-steps of flight), counted vmcnt(6) (= 1 stage in flight).
// Wave grid 4M x 2N, wave tile 64x64, acc[4][4] -> 2.0 MFMA per ds_read.
// MODE 0: h = relu(x[perm] @ W1t^T + b1) -> hb
template <int MODE>
__global__ __launch_bounds__(512, 1) void moe_gemm_deep_kernel(
    const unsigned short* __restrict__ Abase,
    const unsigned short* __restrict__ Wt,   // bf16 [E][1024(n)][1024(k)]
    const float* __restrict__ bias,          // [E][1024]
    const int* __restrict__ offsets, const int* __restrict__ perm,
    unsigned short* __restrict__ hb, float* __restrict__ out) {
  __shared__ __align__(16) unsigned short As[3][256 * 64];  // 96 KB
  __shared__ __align__(16) unsigned short Bs[3][128 * 64];  // 48 KB

  const int e = blockIdx.x & 7;
  const int slot = blockIdx.x >> 3;   // 0..255 per expert
  const int g0 = offsets[e];
  const int m_count = offsets[e + 1] - g0;
  const int m0 = (slot >> 3) * 256;   // 32 m-slots: covers any routing skew
  if (m0 >= m_count) return;          // uniform early-exit, before any barrier
  const int n0 = (slot & 7) * 128;

  const int tid = threadIdx.x;
  const int wid = tid >> 6, lane = tid & 63;  // wid 0..7
  const int lrow = lane >> 3;        // 0..7
  const int lchunk = lane & 7;       // 16B chunk within 128B k-row
  const int schunk = lchunk ^ lrow;  // T2 pre-swizzled source chunk

  const unsigned short* ga[4];
  const unsigned short* gb[2];
  int abase[4], bbase[2];
  const unsigned short* WtE = Wt + ((size_t)e << 20);
#pragma unroll
  for (int t = 0; t < 4; t++) {
    const int rbase = (wid * 4 + t) * 8;  // wave-uniform, rows 0..255
    const int r = rbase + lrow;
    int gr = g0 + m0 + r;
    if (gr > N_TOK - 1) gr = N_TOK - 1;  // clamp partial m-tiles
    const int arow = (MODE == 0) ? perm[gr] : gr;
    ga[t] = Abase + (size_t)arow * 1024 + schunk * 8;
    abase[t] = rbase * 64;  // linear LDS dest, wave-uniform (required)
  }
#pragma unroll
  for (int t = 0; t < 2; t++) {
    const int rbase = (wid * 2 + t) * 8;  // rows 0..127
    const int r = rbase + lrow;
    gb[t] = WtE + (size_t)(n0 + r) * 1024 + schunk * 8;
    bbase[t] = rbase * 64;
  }

  f32x4 acc[4][4];
  const f32x4 zero4 = {0.f, 0.f, 0.f, 0.f};
#pragma unroll
  for (int i = 0; i < 4; i++)
#pragma unroll
    for (int j = 0; j < 4; j++) acc[i][j] = zero4;

  const int wr = wid >> 1, wc = wid & 1;  // 4m x 2n, wave tile 64x64
  const int lr = lane & 15, lk = lane >> 4;

  auto stage = [&](int buf) {
#pragma unroll
    for (int t = 0; t < 4; t++) {
      load_lds16(ga[t], &As[buf][abase[t]]);
      ga[t] += 64;
    }
#pragma unroll
    for (int t = 0; t < 2; t++) {
      load_lds16(gb[t], &Bs[buf][bbase[t]]);
      gb[t] += 64;
    }
  };
  auto compute = [&](int buf) {
#pragma unroll
    for (int kk = 0; kk < 64; kk += 32) {
      bf16x8 af[4], bfr[4];
#pragma unroll
      for (int mf = 0; mf < 4; mf++) {
        const int ra = wr * 64 + mf * 16 + lr;       // 0..255
        const int ca = ((kk >> 3) + lk) ^ (ra & 7);  // swizzled read chunk
        af[mf] = *reinterpret_cast<const bf16x8*>(&As[buf][ra * 64 + ca * 8]);
      }
#pragma unroll
      for (int nf = 0; nf < 4; nf++) {
        const int rb = wc * 64 + nf * 16 + lr;       // 0..127
        const int cb = ((kk >> 3) + lk) ^ (rb & 7);
        bfr[nf] = *reinterpret_cast<const bf16x8*>(&Bs[buf][rb * 64 + cb * 8]);
      }
#pragma unroll
      for (int mf = 0; mf < 4; mf++)
#pragma unroll
        for (int nf = 0; nf < 4; nf++)
          acc[mf][nf] = __builtin_amdgcn_mfma_f32_16x16x32_bf16(
              af[mf], bfr[nf], acc[mf][nf], 0, 0, 0);
    }
  };

  stage(0);
  stage(1);
#pragma unroll
  for (int kt = 0; kt < 16; kt++) {
    if (kt < 15) {
      asm volatile("s_waitcnt vmcnt(6)" ::: "memory");  // tile kt landed
    } else {
      asm volatile("s_waitcnt vmcnt(0)" ::: "memory");
    }
    __builtin_amdgcn_sched_barrier(0);
    __builtin_amdgcn_s_barrier();          // single barrier per K-step
    if (kt < 14) stage((kt + 2) % 3);      // issue-early, 2-step lead
    __builtin_amdgcn_s_setprio(1);
    compute(kt % 3);
    __builtin_amdgcn_s_setprio(0);
  }

  // epilogue: C/D layout col=lane&15, row=(lane>>4)*4+reg [m89]
  const int mlim = m_count - m0;
#pragma unroll
  for (int nf = 0; nf < 4; nf++) {
    const int c = n0 + wc * 64 + nf * 16 + lr;
    const float bval = bias[(e << 10) + c];
#pragma unroll
    for (int mf = 0; mf < 4; mf++) {
#pragma unroll
      for (int j = 0; j < 4; j++) {
        const int lrow2 = wr * 64 + mf * 16 + lk * 4 + j;
        if (lrow2 < mlim) {
          float v = acc[mf][nf][j] + bval;
          if (MODE == 0) {
            v = v > 0.f ? v : 0.f;
            hb[(size_t)(g0 + m0 + lrow2) * 1024 + c] = f32_to_bf16_bits(v);
          } else {
            int token = perm[g0 + m0 + lrow2];
            out[(size_t)token * 1024 + c] = v;
          }
        }
      }
    }
  }
}

// ---------- CONTROL: R7-exact grouped GEMM 128x64, BK=64, 4 waves ----------
template <int MODE, int BK>
__global__ __launch_bounds__(256) void moe_gemm_kernel(
    const unsigned short* __restrict__ Abase,
    const unsigned short* __restrict__ Wt,
    const float* __restrict__ bias,
    const int* __restrict__ offsets, const int* __restrict__ perm,
    unsigned short* __restrict__ hb, float* __restrict__ out,
    int gemm_blocks) {
  constexpr int NCH = BK / 8;
  constexpr int RPL = 64 / NCH;
  constexpr int ALW = 32 / RPL;
  constexpr int BLW = 16 / RPL;
  constexpr int KSTEPS = 1024 / BK;
  __shared__ __align__(16) unsigned short As[2][128 * BK];
  __shared__ __align__(16) unsigned short Bs[2][64 * BK];

  const int e = blockIdx.x & 7;
  const int slot = blockIdx.x >> 3;
  const int g0 = offsets[e];
  const int m_count = offsets[e + 1] - g0;
  const int m0 = (slot >> 4) * 128;
  if (m0 >= m_count) return;
  const int n0 = (slot & 15) * 64;

  const int tid = threadIdx.x;
  const int wid = tid >> 6, lane = tid & 63;
  const int lrow = lane / NCH;
  const int lchunk = lane & (NCH - 1);
  const int schunk = lchunk ^ (lrow & (NCH - 1));

  const unsigned short* ga[ALW];
  const unsigned short* gb[BLW];
  int abase[ALW], bbase[BLW];
  const unsigned short* WtE = Wt + ((size_t)e << 20);
#pragma unroll
  for (int t = 0; t < ALW; t++) {
    const int rbase = (wid * ALW + t) * RPL;
    const int r = rbase + lrow;
    int gr = g0 + m0 + r;
    if (gr > N_TOK - 1) gr = N_TOK - 1;
    const int arow = (MODE == 0) ? perm[gr] : gr;
    ga[t] = Abase + (size_t)arow * 1024 + schunk * 8;
    abase[t] = rbase * BK;
  }
#pragma unroll
  for (int t = 0; t < BLW; t++) {
    const int rbase = (wid * BLW + t) * RPL;
    const int r = rbase + lrow;
    gb[t] = WtE + (size_t)(n0 + r) * 1024 + schunk * 8;
    bbase[t] = rbase * BK;
  }

  f32x4 acc[4][2];
  const f32x4 zero4 = {0.f, 0.f, 0.f, 0.f};
#pragma unroll
  for (int i = 0; i < 4; i++)
#pragma unroll
    for (int j = 0; j < 2; j++) acc[i][j] = zero4;

  const int wr = wid >> 1, wc = wid & 1;
  const int lr = lane & 15, lk = lane >> 4;

  auto stage = [&](int buf) {
#pragma unroll
    for (int t = 0; t < ALW; t++) {
      load_lds16(ga[t], &As[buf][abase[t]]);
      ga[t] += BK;
    }
#pragma unroll
    for (int t = 0; t < BLW; t++) {
      load_lds16(gb[t], &Bs[buf][bbase[t]]);
      gb[t] += BK;
    }
  };
  auto compute = [&](int buf) {
#pragma unroll
    for (int kk = 0; kk < BK; kk += 32) {
      bf16x8 af[4], bfr[2];
#pragma unroll
      for (int mf = 0; mf < 4; mf++) {
        const int ra = wr * 64 + mf * 16 + lr;
        const int ca = ((kk >> 3) + lk) ^ (ra & (NCH - 1));
        af[mf] = *reinterpret_cast<const bf16x8*>(&As[buf][ra * BK + ca * 8]);
      }
#pragma unroll
      for (int nf = 0; nf < 2; nf++) {
        const int rb = wc * 32 + nf * 16 + lr;
        const int cb = ((kk >> 3) + lk) ^ (rb & (NCH - 1));
        bfr[nf] = *reinterpret_cast<const bf16x8*>(&Bs[buf][rb * BK + cb * 8]);
      }
#pragma unroll
      for (int mf = 0; mf < 4; mf++)
#pragma unroll
        for (int nf = 0; nf < 2; nf++)
          acc[mf][nf] = __builtin_amdgcn_mfma_f32_16x16x32_bf16(
              af[mf], bfr[nf], acc[mf][nf], 0, 0, 0);
    }
  };

  stage(0);
  stage(1);
#pragma unroll
  for (int kt = 0; kt < KSTEPS; kt++) {
    if (kt < KSTEPS - 1) {
      asm volatile("s_waitcnt vmcnt(6)" ::: "memory");
    } else {
      asm volatile("s_waitcnt vmcnt(0)" ::: "memory");
    }
    __builtin_amdgcn_sched_barrier(0);
    __builtin_amdgcn_s_barrier();
    __builtin_amdgcn_s_setprio(1);
    compute(kt & 1);
    __builtin_amdgcn_s_setprio(0);
    __builtin_amdgcn_s_barrier();
    if (kt < KSTEPS - 2) stage(kt & 1);
  }

  const int mlim = m_count - m0;
#pragma unroll
  for (int nf = 0; nf < 2; nf++) {
    const int c = n0 + wc * 32 + nf * 16 + lr;
    const float bval = bias[(e << 10) + c];
#pragma unroll
    for (int mf = 0; mf < 4; mf++) {
#pragma unroll
      for (int j = 0; j < 4; j++) {
        const int lrow2 = wr * 64 + mf * 16 + lk * 4 + j;
        if (lrow2 < mlim) {
          float v = acc[mf][nf][j] + bval;
          if (MODE == 0) {
            v = v > 0.f ? v : 0.f;
            hb[(size_t)(g0 + m0 + lrow2) * 1024 + c] = f32_to_bf16_bits(v);
          } else {
            int token = perm[g0 + m0 + lrow2];
            out[(size_t)token * 1024 + c] = v;
          }
        }
      }
    }
  }
}

// ---------- launch ----------
extern "C" void kernel_launch(void* const* d_in, const int* in_sizes, int n_in,
                              void* d_out, int out_size, void* d_ws, size_t ws_size,
                              hipStream_t stream) {
  const float* x = (const float*)d_in[0];
  const float* Wp = (const float*)d_in[1];
  const float* bp = (const float*)d_in[2];
  const float* W1 = (const float*)d_in[3];
  const float* b1 = (const float*)d_in[4];
  const float* W2 = (const float*)d_in[5];
  const float* b2 = (const float*)d_in[6];

  float* out = (float*)d_out;                      // [8192][1024]
  float* probs = out + (size_t)N_TOK * D_DIM;      // [8192][8]
  float* chosenF = probs + (size_t)N_TOK * E_NUM;  // [8192]

  char* ws = (char*)d_ws;
  int* chosen = (int*)(ws + 0);       // 32 KB
  int* perm = (int*)(ws + 32768);     // 32 KB
  float* WpT = (float*)(ws + 65536);  // 32 KB
  int* offsets = (int*)(ws + 98304);  // 64 B
  const size_t MB16 = 16777216;
  unsigned short* xb = (unsigned short*)(ws + 131072);          // 16 MB
  unsigned short* Wt1 = (unsigned short*)(ws + 131072 + MB16);  // 16 MB
  // overlap path: Wt2 separate, W2T rides in the routing launch;
  // fallback: Wt2 aliases Wt1, W2T runs sequentially after GEMM1.
  const bool overlap = ws_size >= 131072 + 4 * MB16;
  unsigned short* Wt2 = (unsigned short*)(ws + 131072 + (overlap ? 2 : 1) * MB16);
  unsigned short* hb = (unsigned short*)(ws + 131072 + (overlap ? 3 : 2) * MB16);

  wpt_kernel<<<32, 256, 0, stream>>>(Wp, WpT);
  routing_w1t_kernel<<<overlap ? 6144 : 4096, 256, 0, stream>>>(
      x, WpT, bp, probs, chosenF, chosen, xb, W1, Wt1, W2, Wt2);
  scan_scatter_kernel<<<E_NUM, 256, 0, stream>>>(chosen, offsets, perm);
  // GEMM1 = deep-pipeline experiment (2048 blocks, 512 thr, 144KB LDS)
  moe_gemm_deep_kernel<0><<<E_NUM * 32 * 8, 512, 0, stream>>>(
      xb, Wt1, b1, offsets, perm, hb, nullptr);
  if (!overlap) {
    transpose_cast_kernel<<<dim3(16, 16, 8), 256, 0, stream>>>(W2, Wt2);
  }
  // GEMM2 = R7-exact control (8192 blocks, 256 thr, 48KB LDS)
  moe_gemm_kernel<1, 64><<<E_NUM * 64 * 16, 256, 0, stream>>>(
      hb, Wt2, b2, offsets, perm, nullptr, out, E_NUM * 64 * 16);
}

// Round 12
// 141.810 us; speedup vs baseline: 1.0539x; 1.0539x over previous
//
#include <hip/hip_runtime.h>
#include <stdint.h>

#define N_TOK 8192
#define D_DIM 1024
#define E_NUM 8

typedef float f32x4 __attribute__((ext_vector_type(4)));
typedef __bf16 bf16x8 __attribute__((ext_vector_type(8)));

__device__ __forceinline__ unsigned short f32_to_bf16_bits(float f) {
  union { float f; uint32_t u; } v; v.f = f;
  uint32_t u = v.u;
  uint32_t r = u + 0x7fffu + ((u >> 16) & 1u);  // RNE
  return (unsigned short)(r >> 16);
}

__device__ __forceinline__ void load_lds16(const void* g, void* l) {
  // async global->LDS, 16B/lane, dest = uniform base + lane*16
  __builtin_amdgcn_global_load_lds(
      (const __attribute__((address_space(1))) void*)g,
      (__attribute__((address_space(3))) void*)l, 16, 0, 0);
}

// ---------- shared 64x64 fp32->bf16 transpose tile (LDS-staged) ----------
__device__ __forceinline__ void transpose_tile(unsigned short (*T)[72],
                                               const float* __restrict__ S,
                                               unsigned short* __restrict__ O,
                                               int r0, int c0, int t) {
  const int rr = t >> 4;
  const int cc = (t & 15) * 4;
#pragma unroll
  for (int p = 0; p < 4; p++) {
    int r = p * 16 + rr;
    float4 v = *reinterpret_cast<const float4*>(S + (size_t)(r0 + r) * 1024 + c0 + cc);
    T[cc + 0][r] = f32_to_bf16_bits(v.x);
    T[cc + 1][r] = f32_to_bf16_bits(v.y);
    T[cc + 2][r] = f32_to_bf16_bits(v.z);
    T[cc + 3][r] = f32_to_bf16_bits(v.w);
  }
  __syncthreads();
#pragma unroll
  for (int p = 0; p < 4; p++) {
    int c = p * 16 + rr;
    ushort4 o = *reinterpret_cast<const ushort4*>(&T[c][cc]);
    *reinterpret_cast<ushort4*>(O + (size_t)(c0 + c) * 1024 + r0 + cc) = o;
  }
}

// ---------- Wp [1024][8] -> WpT [8][1024] ----------
__global__ __launch_bounds__(256) void wpt_kernel(const float* __restrict__ Wp,
                                                  float* __restrict__ WpT) {
  int i = blockIdx.x * 256 + threadIdx.x;  // 8192 total
  int e = i >> 10, d = i & 1023;
  WpT[i] = Wp[(size_t)d * E_NUM + e];
}

// ---------- fused: routing (fp64 logits) + x->bf16 + W1T + W2T ----------
// bids 0..2047 routing; 2048..4095 W1 transpose; 4096..6143 W2 transpose
// (overlap path only). fp64 logits so argmax matches the np reference.
// NO global atomics (R3: same-line atomicAdds serialized ~70us of tail).
__global__ __launch_bounds__(256) void routing_w1t_kernel(
    const float* __restrict__ x, const float* __restrict__ WpT,
    const float* __restrict__ bp, float* __restrict__ probs_out,
    float* __restrict__ chosenF, int* __restrict__ chosen,
    unsigned short* __restrict__ xb,
    const float* __restrict__ W1, unsigned short* __restrict__ W1t,
    const float* __restrict__ W2, unsigned short* __restrict__ W2t) {
  __shared__ __align__(16) unsigned short T[64][72];
  __shared__ __align__(16) float pbuf[4][8];
  if (blockIdx.x >= 4096) {  // W2 transpose role
    const int tb = blockIdx.x - 4096;
    const int e = tb >> 8, rc = tb & 255;
    transpose_tile(T, W2 + ((size_t)e << 20), W2t + ((size_t)e << 20),
                   (rc >> 4) * 64, (rc & 15) * 64, threadIdx.x);
    return;
  }
  if (blockIdx.x >= 2048) {  // W1 transpose role
    const int tb = blockIdx.x - 2048;
    const int e = tb >> 8, rc = tb & 255;
    transpose_tile(T, W1 + ((size_t)e << 20), W1t + ((size_t)e << 20),
                   (rc >> 4) * 64, (rc & 15) * 64, threadIdx.x);
    return;
  }
  const int wave = threadIdx.x >> 6;
  const int lane = threadIdx.x & 63;
  const int token = blockIdx.x * 4 + wave;
  const float* xr = x + (size_t)token * D_DIM;
  unsigned short* xbr = xb + (size_t)token * D_DIM;
  double acc[E_NUM];
#pragma unroll
  for (int e = 0; e < E_NUM; e++) acc[e] = 0.0;
#pragma unroll
  for (int it = 0; it < 4; it++) {
    const int d0 = it * 256 + lane * 4;
    float4 xv = *reinterpret_cast<const float4*>(xr + d0);
    ushort4 o;
    o.x = f32_to_bf16_bits(xv.x);
    o.y = f32_to_bf16_bits(xv.y);
    o.z = f32_to_bf16_bits(xv.z);
    o.w = f32_to_bf16_bits(xv.w);
    *reinterpret_cast<ushort4*>(xbr + d0) = o;
#pragma unroll
    for (int e = 0; e < E_NUM; e++) {
      float4 w = *reinterpret_cast<const float4*>(WpT + (e << 10) + d0);  // coalesced
      acc[e] += (double)xv.x * (double)w.x;
      acc[e] += (double)xv.y * (double)w.y;
      acc[e] += (double)xv.z * (double)w.z;
      acc[e] += (double)xv.w * (double)w.w;
    }
  }
#pragma unroll
  for (int e = 0; e < E_NUM; e++) {
#pragma unroll
    for (int off = 32; off > 0; off >>= 1) acc[e] += __shfl_xor(acc[e], off);
  }
  if (lane == 0) {
    double lg[E_NUM];
#pragma unroll
    for (int e = 0; e < E_NUM; e++) lg[e] = acc[e] + (double)bp[e];
    int best = 0;
    double bv = lg[0];
#pragma unroll
    for (int e = 1; e < E_NUM; e++)
      if (lg[e] > bv) { bv = lg[e]; best = e; }  // strict > == first-max (jnp.argmax)
    double s = 0.0, ex[E_NUM];
#pragma unroll
    for (int e = 0; e < E_NUM; e++) { ex[e] = exp(lg[e] - bv); s += ex[e]; }
    double inv = 1.0 / s;
#pragma unroll
    for (int e = 0; e < E_NUM; e++) pbuf[wave][e] = (float)(ex[e] * inv);
    chosenF[token] = (float)best;
    chosen[token] = best;
  }
  __syncthreads();
  if (threadIdx.x < 8) {  // coalesced 128B probs store per block
    float4 v = *reinterpret_cast<const float4*>(
        &pbuf[threadIdx.x >> 1][(threadIdx.x & 1) * 4]);
    reinterpret_cast<float4*>(probs_out + (size_t)blockIdx.x * 32)[threadIdx.x] = v;
  }
}

// ---------- scan + scatter, 8 blocks (one per expert), LDS atomics only ----------
__global__ __launch_bounds__(256) void scan_scatter_kernel(
    const int* __restrict__ chosen, int* __restrict__ offsets,
    int* __restrict__ perm) {
  __shared__ int hist[E_NUM];
  __shared__ int cur;
  const int e = blockIdx.x;
  const int t = threadIdx.x;
  if (t < E_NUM) hist[t] = 0;
  __syncthreads();
  for (int n = t; n < N_TOK; n += 256) atomicAdd(&hist[chosen[n]], 1);
  __syncthreads();
  if (t == 0) {
    int off = 0;
    for (int i = 0; i < e; i++) off += hist[i];
    cur = off;
    if (e == 0) {
      int o = 0;
      for (int i = 0; i < E_NUM; i++) { offsets[i] = o; o += hist[i]; }
      offsets[E_NUM] = o;
    }
  }
  __syncthreads();
  for (int n = t; n < N_TOK; n += 256) {
    if (chosen[n] == e) {
      int p = atomicAdd(&cur, 1);  // in-group order irrelevant
      perm[p] = n;
    }
  }
}

// ---------- standalone per-expert transpose (sequential fallback path) ----------
__global__ __launch_bounds__(256) void transpose_cast_kernel(
    const float* __restrict__ src, unsigned short* __restrict__ dst) {
  __shared__ __align__(16) unsigned short T[64][72];
  const int e = blockIdx.z;
  transpose_tile(T, src + ((size_t)e << 20), dst + ((size_t)e << 20),
                 blockIdx.y * 64, blockIdx.x * 64, threadIdx.x);
}

// ---------- R12 EXPERIMENT: 128x128 tile, 4 waves (2x2), wave tile 64x64 ----------
// Last untested {shape x schedule} cell: ratio-32 FLOP/LDS-byte (1.5x R7's
// 21.3) under the PROVEN R7 counted-vmcnt schedule. 512 active blocks (2/CU,
// 64KB dbuf LDS). R5 tested this shape only with the naive schedule; R8/R11
// failed at 1-block/CU. Per-CU per-K-step arithmetic: LDS demand 576->512cyc,
// MFMA demand 234->320cyc -- if the LDS issue path is the serializer, this
// moves it. acc[4][4] (64 VGPR). 8 loads/thread/stage -> steady vmcnt(8).
// MODE 0: h = relu(x[perm] @ W1t^T + b1) -> hb
template <int MODE>
__global__ __launch_bounds__(256) void moe_gemm_wide_kernel(
    const unsigned short* __restrict__ Abase,
    const unsigned short* __restrict__ Wt,   // bf16 [E][1024(n)][1024(k)]
    const float* __restrict__ bias,          // [E][1024]
    const int* __restrict__ offsets, const int* __restrict__ perm,
    unsigned short* __restrict__ hb, float* __restrict__ out) {
  __shared__ __align__(16) unsigned short As[2][128 * 64];  // 32 KB
  __shared__ __align__(16) unsigned short Bs[2][128 * 64];  // 32 KB

  const int e = blockIdx.x & 7;
  const int slot = blockIdx.x >> 3;   // 0..511 per expert
  const int g0 = offsets[e];
  const int m_count = offsets[e + 1] - g0;
  const int m0 = (slot >> 3) * 128;   // 64 m-tiles: covers any routing skew
  if (m0 >= m_count) return;          // uniform early-exit, before any barrier
  const int n0 = (slot & 7) * 128;

  const int tid = threadIdx.x;
  const int wid = tid >> 6, lane = tid & 63;
  const int lrow = lane >> 3;        // 0..7
  const int lchunk = lane & 7;       // 16B chunk within 128B k-row
  const int schunk = lchunk ^ lrow;  // T2 pre-swizzled source chunk

  const unsigned short* ga[4];
  const unsigned short* gb[4];
  int abase[4], bbase[4];
  const unsigned short* WtE = Wt + ((size_t)e << 20);
#pragma unroll
  for (int t = 0; t < 4; t++) {
    const int rbase = t * 32 + wid * 8;  // wave-uniform, rows 0..127
    const int r = rbase + lrow;
    int gr = g0 + m0 + r;
    if (gr > N_TOK - 1) gr = N_TOK - 1;  // clamp partial m-tiles
    const int arow = (MODE == 0) ? perm[gr] : gr;
    ga[t] = Abase + (size_t)arow * 1024 + schunk * 8;
    abase[t] = rbase * 64;  // linear LDS dest, wave-uniform (required)
    gb[t] = WtE + (size_t)(n0 + r) * 1024 + schunk * 8;
    bbase[t] = rbase * 64;
  }

  f32x4 acc[4][4];
  const f32x4 zero4 = {0.f, 0.f, 0.f, 0.f};
#pragma unroll
  for (int i = 0; i < 4; i++)
#pragma unroll
    for (int j = 0; j < 4; j++) acc[i][j] = zero4;

  const int wr = wid >> 1, wc = wid & 1;  // 2x2 waves, wave tile 64x64
  const int lr = lane & 15, lk = lane >> 4;

  auto stage = [&](int buf) {
#pragma unroll
    for (int t = 0; t < 4; t++) {
      load_lds16(ga[t], &As[buf][abase[t]]);
      ga[t] += 64;
      load_lds16(gb[t], &Bs[buf][bbase[t]]);
      gb[t] += 64;
    }
  };
  auto compute = [&](int buf) {
#pragma unroll
    for (int kk = 0; kk < 64; kk += 32) {
      bf16x8 af[4], bfr[4];
#pragma unroll
      for (int mf = 0; mf < 4; mf++) {
        const int ra = wr * 64 + mf * 16 + lr;       // 0..127
        const int ca = ((kk >> 3) + lk) ^ (ra & 7);  // swizzled read chunk
        af[mf] = *reinterpret_cast<const bf16x8*>(&As[buf][ra * 64 + ca * 8]);
      }
#pragma unroll
      for (int nf = 0; nf < 4; nf++) {
        const int rb = wc * 64 + nf * 16 + lr;       // 0..127
        const int cb = ((kk >> 3) + lk) ^ (rb & 7);
        bfr[nf] = *reinterpret_cast<const bf16x8*>(&Bs[buf][rb * 64 + cb * 8]);
      }
#pragma unroll
      for (int mf = 0; mf < 4; mf++)
#pragma unroll
        for (int nf = 0; nf < 4; nf++)
          acc[mf][nf] = __builtin_amdgcn_mfma_f32_16x16x32_bf16(
              af[mf], bfr[nf], acc[mf][nf], 0, 0, 0);
    }
  };

  // R7 counted-vmcnt schedule, 8 loads/thread/stage
  stage(0);
  stage(1);
#pragma unroll
  for (int kt = 0; kt < 16; kt++) {
    if (kt < 15) {
      asm volatile("s_waitcnt vmcnt(8)" ::: "memory");  // tile kt landed
    } else {
      asm volatile("s_waitcnt vmcnt(0)" ::: "memory");
    }
    __builtin_amdgcn_sched_barrier(0);
    __builtin_amdgcn_s_barrier();  // tile kt ready for all waves
    __builtin_amdgcn_s_setprio(1);
    compute(kt & 1);
    __builtin_amdgcn_s_setprio(0);
    __builtin_amdgcn_s_barrier();        // all waves done reading buf[kt&1]
    if (kt < 14) stage(kt & 1);          // tile kt+2 overwrites buf[kt&1]
  }

  // epilogue: C/D layout col=lane&15, row=(lane>>4)*4+reg [m89]
  const int mlim = m_count - m0;
#pragma unroll
  for (int nf = 0; nf < 4; nf++) {
    const int c = n0 + wc * 64 + nf * 16 + lr;
    const float bval = bias[(e << 10) + c];
#pragma unroll
    for (int mf = 0; mf < 4; mf++) {
#pragma unroll
      for (int j = 0; j < 4; j++) {
        const int lrow2 = wr * 64 + mf * 16 + lk * 4 + j;
        if (lrow2 < mlim) {
          float v = acc[mf][nf][j] + bval;
          if (MODE == 0) {
            v = v > 0.f ? v : 0.f;
            hb[(size_t)(g0 + m0 + lrow2) * 1024 + c] = f32_to_bf16_bits(v);
          } else {
            int token = perm[g0 + m0 + lrow2];
            out[(size_t)token * 1024 + c] = v;
          }
        }
      }
    }
  }
}

// ---------- CONTROL: R7-exact grouped GEMM 128x64, BK=64, 4 waves ----------
template <int MODE, int BK>
__global__ __launch_bounds__(256) void moe_gemm_kernel(
    const unsigned short* __restrict__ Abase,
    const unsigned short* __restrict__ Wt,
    const float* __restrict__ bias,
    const int* __restrict__ offsets, const int* __restrict__ perm,
    unsigned short* __restrict__ hb, float* __restrict__ out,
    int gemm_blocks) {
  constexpr int NCH = BK / 8;
  constexpr int RPL = 64 / NCH;
  constexpr int ALW = 32 / RPL;
  constexpr int BLW = 16 / RPL;
  constexpr int KSTEPS = 1024 / BK;
  __shared__ __align__(16) unsigned short As[2][128 * BK];
  __shared__ __align__(16) unsigned short Bs[2][64 * BK];

  const int e = blockIdx.x & 7;
  const int slot = blockIdx.x >> 3;
  const int g0 = offsets[e];
  const int m_count = offsets[e + 1] - g0;
  const int m0 = (slot >> 4) * 128;
  if (m0 >= m_count) return;
  const int n0 = (slot & 15) * 64;

  const int tid = threadIdx.x;
  const int wid = tid >> 6, lane = tid & 63;
  const int lrow = lane / NCH;
  const int lchunk = lane & (NCH - 1);
  const int schunk = lchunk ^ (lrow & (NCH - 1));

  const unsigned short* ga[ALW];
  const unsigned short* gb[BLW];
  int abase[ALW], bbase[BLW];
  const unsigned short* WtE = Wt + ((size_t)e << 20);
#pragma unroll
  for (int t = 0; t < ALW; t++) {
    const int rbase = (wid * ALW + t) * RPL;
    const int r = rbase + lrow;
    int gr = g0 + m0 + r;
    if (gr > N_TOK - 1) gr = N_TOK - 1;
    const int arow = (MODE == 0) ? perm[gr] : gr;
    ga[t] = Abase + (size_t)arow * 1024 + schunk * 8;
    abase[t] = rbase * BK;
  }
#pragma unroll
  for (int t = 0; t < BLW; t++) {
    const int rbase = (wid * BLW + t) * RPL;
    const int r = rbase + lrow;
    gb[t] = WtE + (size_t)(n0 + r) * 1024 + schunk * 8;
    bbase[t] = rbase * BK;
  }

  f32x4 acc[4][2];
  const f32x4 zero4 = {0.f, 0.f, 0.f, 0.f};
#pragma unroll
  for (int i = 0; i < 4; i++)
#pragma unroll
    for (int j = 0; j < 2; j++) acc[i][j] = zero4;

  const int wr = wid >> 1, wc = wid & 1;
  const int lr = lane & 15, lk = lane >> 4;

  auto stage = [&](int buf) {
#pragma unroll
    for (int t = 0; t < ALW; t++) {
      load_lds16(ga[t], &As[buf][abase[t]]);
      ga[t] += BK;
    }
#pragma unroll
    for (int t = 0; t < BLW; t++) {
      load_lds16(gb[t], &Bs[buf][bbase[t]]);
      gb[t] += BK;
    }
  };
  auto compute = [&](int buf) {
#pragma unroll
    for (int kk = 0; kk < BK; kk += 32) {
      bf16x8 af[4], bfr[2];
#pragma unroll
      for (int mf = 0; mf < 4; mf++) {
        const int ra = wr * 64 + mf * 16 + lr;
        const int ca = ((kk >> 3) + lk) ^ (ra & (NCH - 1));
        af[mf] = *reinterpret_cast<const bf16x8*>(&As[buf][ra * BK + ca * 8]);
      }
#pragma unroll
      for (int nf = 0; nf < 2; nf++) {
        const int rb = wc * 32 + nf * 16 + lr;
        const int cb = ((kk >> 3) + lk) ^ (rb & (NCH - 1));
        bfr[nf] = *reinterpret_cast<const bf16x8*>(&Bs[buf][rb * BK + cb * 8]);
      }
#pragma unroll
      for (int mf = 0; mf < 4; mf++)
#pragma unroll
        for (int nf = 0; nf < 2; nf++)
          acc[mf][nf] = __builtin_amdgcn_mfma_f32_16x16x32_bf16(
              af[mf], bfr[nf], acc[mf][nf], 0, 0, 0);
    }
  };

  stage(0);
  stage(1);
#pragma unroll
  for (int kt = 0; kt < KSTEPS; kt++) {
    if (kt < KSTEPS - 1) {
      asm volatile("s_waitcnt vmcnt(6)" ::: "memory");
    } else {
      asm volatile("s_waitcnt vmcnt(0)" ::: "memory");
    }
    __builtin_amdgcn_sched_barrier(0);
    __builtin_amdgcn_s_barrier();
    __builtin_amdgcn_s_setprio(1);
    compute(kt & 1);
    __builtin_amdgcn_s_setprio(0);
    __builtin_amdgcn_s_barrier();
    if (kt < KSTEPS - 2) stage(kt & 1);
  }

  const int mlim = m_count - m0;
#pragma unroll
  for (int nf = 0; nf < 2; nf++) {
    const int c = n0 + wc * 32 + nf * 16 + lr;
    const float bval = bias[(e << 10) + c];
#pragma unroll
    for (int mf = 0; mf < 4; mf++) {
#pragma unroll
      for (int j = 0; j < 4; j++) {
        const int lrow2 = wr * 64 + mf * 16 + lk * 4 + j;
        if (lrow2 < mlim) {
          float v = acc[mf][nf][j] + bval;
          if (MODE == 0) {
            v = v > 0.f ? v : 0.f;
            hb[(size_t)(g0 + m0 + lrow2) * 1024 + c] = f32_to_bf16_bits(v);
          } else {
            int token = perm[g0 + m0 + lrow2];
            out[(size_t)token * 1024 + c] = v;
          }
        }
      }
    }
  }
}

// ---------- launch ----------
extern "C" void kernel_launch(void* const* d_in, const int* in_sizes, int n_in,
                              void* d_out, int out_size, void* d_ws, size_t ws_size,
                              hipStream_t stream) {
  const float* x = (const float*)d_in[0];
  const float* Wp = (const float*)d_in[1];
  const float* bp = (const float*)d_in[2];
  const float* W1 = (const float*)d_in[3];
  const float* b1 = (const float*)d_in[4];
  const float* W2 = (const float*)d_in[5];
  const float* b2 = (const float*)d_in[6];

  float* out = (float*)d_out;                      // [8192][1024]
  float* probs = out + (size_t)N_TOK * D_DIM;      // [8192][8]
  float* chosenF = probs + (size_t)N_TOK * E_NUM;  // [8192]

  char* ws = (char*)d_ws;
  int* chosen = (int*)(ws + 0);       // 32 KB
  int* perm = (int*)(ws + 32768);     // 32 KB
  float* WpT = (float*)(ws + 65536);  // 32 KB
  int* offsets = (int*)(ws + 98304);  // 64 B
  const size_t MB16 = 16777216;
  unsigned short* xb = (unsigned short*)(ws + 131072);          // 16 MB
  unsigned short* Wt1 = (unsigned short*)(ws + 131072 + MB16);  // 16 MB
  // overlap path: Wt2 separate, W2T rides in the routing launch;
  // fallback: Wt2 aliases Wt1, W2T runs sequentially after GEMM1.
  const bool overlap = ws_size >= 131072 + 4 * MB16;
  unsigned short* Wt2 = (unsigned short*)(ws + 131072 + (overlap ? 2 : 1) * MB16);
  unsigned short* hb = (unsigned short*)(ws + 131072 + (overlap ? 3 : 2) * MB16);

  wpt_kernel<<<32, 256, 0, stream>>>(Wp, WpT);
  routing_w1t_kernel<<<overlap ? 6144 : 4096, 256, 0, stream>>>(
      x, WpT, bp, probs, chosenF, chosen, xb, W1, Wt1, W2, Wt2);
  scan_scatter_kernel<<<E_NUM, 256, 0, stream>>>(chosen, offsets, perm);
  // GEMM1 = 128x128 ratio experiment (4096 blocks, 512 active, 64KB LDS)
  moe_gemm_wide_kernel<0><<<E_NUM * 64 * 8, 256, 0, stream>>>(
      xb, Wt1, b1, offsets, perm, hb, nullptr);
  if (!overlap) {
    transpose_cast_kernel<<<dim3(16, 16, 8), 256, 0, stream>>>(W2, Wt2);
  }
  // GEMM2 = R7-exact control (8192 blocks, 256 thr, 48KB LDS)
  moe_gemm_kernel<1, 64><<<E_NUM * 64 * 16, 256, 0, stream>>>(
      hb, Wt2, b2, offsets, perm, nullptr, out, E_NUM * 64 * 16);
}

// Round 13
// 126.144 us; speedup vs baseline: 1.1848x; 1.1242x over previous
//
#include <hip/hip_runtime.h>
#include <stdint.h>

#define N_TOK 8192
#define D_DIM 1024
#define E_NUM 8

typedef float f32x4 __attribute__((ext_vector_type(4)));
typedef __bf16 bf16x8 __attribute__((ext_vector_type(8)));

__device__ __forceinline__ unsigned short f32_to_bf16_bits(float f) {
  union { float f; uint32_t u; } v; v.f = f;
  uint32_t u = v.u;
  uint32_t r = u + 0x7fffu + ((u >> 16) & 1u);  // RNE
  return (unsigned short)(r >> 16);
}

__device__ __forceinline__ void load_lds16(const void* g, void* l) {
  // async global->LDS, 16B/lane, dest = uniform base + lane*16
  __builtin_amdgcn_global_load_lds(
      (const __attribute__((address_space(1))) void*)g,
      (__attribute__((address_space(3))) void*)l, 16, 0, 0);
}

// ---------- shared 64x64 fp32->bf16 transpose tile (LDS-staged) ----------
__device__ __forceinline__ void transpose_tile(unsigned short (*T)[72],
                                               const float* __restrict__ S,
                                               unsigned short* __restrict__ O,
                                               int r0, int c0, int t) {
  const int rr = t >> 4;
  const int cc = (t & 15) * 4;
#pragma unroll
  for (int p = 0; p < 4; p++) {
    int r = p * 16 + rr;
    float4 v = *reinterpret_cast<const float4*>(S + (size_t)(r0 + r) * 1024 + c0 + cc);
    T[cc + 0][r] = f32_to_bf16_bits(v.x);
    T[cc + 1][r] = f32_to_bf16_bits(v.y);
    T[cc + 2][r] = f32_to_bf16_bits(v.z);
    T[cc + 3][r] = f32_to_bf16_bits(v.w);
  }
  __syncthreads();
#pragma unroll
  for (int p = 0; p < 4; p++) {
    int c = p * 16 + rr;
    ushort4 o = *reinterpret_cast<const ushort4*>(&T[c][cc]);
    *reinterpret_cast<ushort4*>(O + (size_t)(c0 + c) * 1024 + r0 + cc) = o;
  }
}

// ---------- Wp [1024][8] -> WpT [8][1024] ----------
__global__ __launch_bounds__(256) void wpt_kernel(const float* __restrict__ Wp,
                                                  float* __restrict__ WpT) {
  int i = blockIdx.x * 256 + threadIdx.x;  // 8192 total
  int e = i >> 10, d = i & 1023;
  WpT[i] = Wp[(size_t)d * E_NUM + e];
}

// ---------- fused: routing (fp64 logits) + x->bf16 + W1 transpose ----------
// bids 0..2047: routing, 4 tokens/block. bids 2048..4095: W1 64x64 transpose tiles.
// fp64 logits so argmax matches the np reference exactly.
// NO global atomics (R3: 8192 same-line atomicAdds serialized ~70us of tail).
__global__ __launch_bounds__(256) void routing_w1t_kernel(
    const float* __restrict__ x, const float* __restrict__ WpT,
    const float* __restrict__ bp, float* __restrict__ probs_out,
    float* __restrict__ chosenF, int* __restrict__ chosen,
    unsigned short* __restrict__ xb,
    const float* __restrict__ W1, unsigned short* __restrict__ W1t) {
  __shared__ __align__(16) unsigned short T[64][72];
  __shared__ __align__(16) float pbuf[4][8];
  if (blockIdx.x >= 2048) {  // transpose role
    const int tb = blockIdx.x - 2048;
    const int e = tb >> 8, rc = tb & 255;
    transpose_tile(T, W1 + ((size_t)e << 20), W1t + ((size_t)e << 20),
                   (rc >> 4) * 64, (rc & 15) * 64, threadIdx.x);
    return;
  }
  const int wave = threadIdx.x >> 6;
  const int lane = threadIdx.x & 63;
  const int token = blockIdx.x * 4 + wave;
  const float* xr = x + (size_t)token * D_DIM;
  unsigned short* xbr = xb + (size_t)token * D_DIM;
  double acc[E_NUM];
#pragma unroll
  for (int e = 0; e < E_NUM; e++) acc[e] = 0.0;
#pragma unroll
  for (int it = 0; it < 4; it++) {
    const int d0 = it * 256 + lane * 4;
    float4 xv = *reinterpret_cast<const float4*>(xr + d0);
    ushort4 o;
    o.x = f32_to_bf16_bits(xv.x);
    o.y = f32_to_bf16_bits(xv.y);
    o.z = f32_to_bf16_bits(xv.z);
    o.w = f32_to_bf16_bits(xv.w);
    *reinterpret_cast<ushort4*>(xbr + d0) = o;
#pragma unroll
    for (int e = 0; e < E_NUM; e++) {
      float4 w = *reinterpret_cast<const float4*>(WpT + (e << 10) + d0);  // coalesced
      acc[e] += (double)xv.x * (double)w.x;
      acc[e] += (double)xv.y * (double)w.y;
      acc[e] += (double)xv.z * (double)w.z;
      acc[e] += (double)xv.w * (double)w.w;
    }
  }
#pragma unroll
  for (int e = 0; e < E_NUM; e++) {
#pragma unroll
    for (int off = 32; off > 0; off >>= 1) acc[e] += __shfl_xor(acc[e], off);
  }
  if (lane == 0) {
    double lg[E_NUM];
#pragma unroll
    for (int e = 0; e < E_NUM; e++) lg[e] = acc[e] + (double)bp[e];
    int best = 0;
    double bv = lg[0];
#pragma unroll
    for (int e = 1; e < E_NUM; e++)
      if (lg[e] > bv) { bv = lg[e]; best = e; }  // strict > == first-max (jnp.argmax)
    double s = 0.0, ex[E_NUM];
#pragma unroll
    for (int e = 0; e < E_NUM; e++) { ex[e] = exp(lg[e] - bv); s += ex[e]; }
    double inv = 1.0 / s;
#pragma unroll
    for (int e = 0; e < E_NUM; e++) pbuf[wave][e] = (float)(ex[e] * inv);
    chosenF[token] = (float)best;
    chosen[token] = best;
  }
  __syncthreads();
  if (threadIdx.x < 8) {  // coalesced 128B probs store per block
    float4 v = *reinterpret_cast<const float4*>(
        &pbuf[threadIdx.x >> 1][(threadIdx.x & 1) * 4]);
    reinterpret_cast<float4*>(probs_out + (size_t)blockIdx.x * 32)[threadIdx.x] = v;
  }
}

// ---------- scan + scatter, 8 blocks (one per expert), LDS atomics only ----------
// Each block redundantly histograms chosen (32KB read, L2-hot) then writes
// only its expert's segment. R10-proven (~2us vs ~5us single-block).
__global__ __launch_bounds__(256) void scan_scatter_kernel(
    const int* __restrict__ chosen, int* __restrict__ offsets,
    int* __restrict__ perm) {
  __shared__ int hist[E_NUM];
  __shared__ int cur;
  const int e = blockIdx.x;
  const int t = threadIdx.x;
  if (t < E_NUM) hist[t] = 0;
  __syncthreads();
  for (int n = t; n < N_TOK; n += 256) atomicAdd(&hist[chosen[n]], 1);
  __syncthreads();
  if (t == 0) {
    int off = 0;
    for (int i = 0; i < e; i++) off += hist[i];
    cur = off;
    if (e == 0) {
      int o = 0;
      for (int i = 0; i < E_NUM; i++) { offsets[i] = o; o += hist[i]; }
      offsets[E_NUM] = o;
    }
  }
  __syncthreads();
  for (int n = t; n < N_TOK; n += 256) {
    if (chosen[n] == e) {
      int p = atomicAdd(&cur, 1);  // in-group order irrelevant
      perm[p] = n;
    }
  }
}

// ---------- standalone per-expert transpose (sequential fallback path) ----------
__global__ __launch_bounds__(256) void transpose_cast_kernel(
    const float* __restrict__ src, unsigned short* __restrict__ dst) {
  __shared__ __align__(16) unsigned short T[64][72];
  const int e = blockIdx.z;
  transpose_tile(T, src + ((size_t)e << 20), dst + ((size_t)e << 20),
                 blockIdx.y * 64, blockIdx.x * 64, threadIdx.x);
}

// ---------- grouped GEMM: 128x64 tile, BK=64, 4 waves — R7-EXACT (measured opt) ----
// R13 consolidation. Full search results (R4-R12, all same-run-comparable):
//   counted-vmcnt 128x64 (this) = 47us; every other {shape, schedule, depth,
//   occupancy} variant = 49-63us. Per-pipe busy at 47us: MFMA 6us, LDS-issue
//   ~15us, VALU ~5us, HBM 19% -> plateau is the lockstep ds_read->MFMA chain,
//   addressable only by an m201-style 8-phase fine interleave (high risk).
// Schedule: prologue stage(t0,t1); steady {vmcnt(6); barrier; setprio(1);
// MFMA; setprio(0); barrier; stage(t+2)} -- never vmcnt(0) mid-loop.
// T2 swizzle per rule #21: linear LDS dest, source chunk ^= lrow, read
// chunk ^= row&7. bids >= gemm_blocks: W2 transpose ride-along (GEMM1 only).
// MODE 0: h = relu(x[perm] @ W1t^T + b1) -> hb   MODE 1: out[perm] = hb @ W2t^T + b2
template <int MODE>
__global__ __launch_bounds__(256) void moe_gemm_kernel(
    const unsigned short* __restrict__ Abase,  // xb (MODE0) / hb (MODE1)
    const unsigned short* __restrict__ Wt,     // bf16 [E][1024(n)][1024(k)]
    const float* __restrict__ bias,            // [E][1024]
    const int* __restrict__ offsets, const int* __restrict__ perm,
    unsigned short* __restrict__ hb, float* __restrict__ out,
    const float* __restrict__ tsrc, unsigned short* __restrict__ tdst,
    int gemm_blocks) {
  __shared__ __align__(16) unsigned short As[2][128 * 64];  // 32 KB
  __shared__ __align__(16) unsigned short Bs[2][64 * 64];   // 16 KB

  if ((int)blockIdx.x >= gemm_blocks) {  // transpose role (MODE 0 overlap path)
    const int tb = blockIdx.x - gemm_blocks;
    const int e = tb >> 8, rc = tb & 255;
    auto T = reinterpret_cast<unsigned short(*)[72]>(&As[0][0]);
    transpose_tile(T, tsrc + ((size_t)e << 20), tdst + ((size_t)e << 20),
                   (rc >> 4) * 64, (rc & 15) * 64, threadIdx.x);
    return;
  }

  const int e = blockIdx.x & 7;
  const int slot = blockIdx.x >> 3;   // 0..1023 per expert
  const int g0 = offsets[e];
  const int m_count = offsets[e + 1] - g0;
  const int m0 = (slot >> 4) * 128;   // 64 m-tiles: covers any routing skew
  if (m0 >= m_count) return;          // uniform early-exit, before any barrier
  const int n0 = (slot & 15) * 64;

  const int tid = threadIdx.x;
  const int wid = tid >> 6, lane = tid & 63;
  const int lrow = lane >> 3;        // 0..7: row within the wave's 8-row stripe
  const int lchunk = lane & 7;       // 16B chunk within the 128B k-row
  const int schunk = lchunk ^ lrow;  // pre-swizzled source chunk (involution)

  const unsigned short* ga[4];
  const unsigned short* gb[2];
  int abase[4], bbase[2];
  const unsigned short* WtE = Wt + ((size_t)e << 20);
#pragma unroll
  for (int t = 0; t < 4; t++) {
    const int rbase = t * 32 + wid * 8;  // wave-uniform, multiple of 8
    const int r = rbase + lrow;          // 0..127
    int gr = g0 + m0 + r;
    if (gr > N_TOK - 1) gr = N_TOK - 1;  // clamp partial m-tiles
    const int arow = (MODE == 0) ? perm[gr] : gr;
    ga[t] = Abase + (size_t)arow * 1024 + schunk * 8;
    abase[t] = rbase * 64;  // linear LDS dest, wave-uniform (required)
  }
#pragma unroll
  for (int t = 0; t < 2; t++) {
    const int rbase = t * 32 + wid * 8;
    const int r = rbase + lrow;  // 0..63
    gb[t] = WtE + (size_t)(n0 + r) * 1024 + schunk * 8;
    bbase[t] = rbase * 64;
  }

  f32x4 acc[4][2];
  const f32x4 zero4 = {0.f, 0.f, 0.f, 0.f};
#pragma unroll
  for (int i = 0; i < 4; i++)
#pragma unroll
    for (int j = 0; j < 2; j++) acc[i][j] = zero4;

  const int wr = wid >> 1, wc = wid & 1;  // wave tile: 64 rows x 32 cols
  const int lr = lane & 15, lk = lane >> 4;

  auto stage = [&](int buf) {
#pragma unroll
    for (int t = 0; t < 4; t++) {
      load_lds16(ga[t], &As[buf][abase[t]]);
      ga[t] += 64;
    }
#pragma unroll
    for (int t = 0; t < 2; t++) {
      load_lds16(gb[t], &Bs[buf][bbase[t]]);
      gb[t] += 64;
    }
  };
  auto compute = [&](int buf) {
#pragma unroll
    for (int kk = 0; kk < 64; kk += 32) {
      bf16x8 af[4], bfr[2];
#pragma unroll
      for (int mf = 0; mf < 4; mf++) {
        const int ra = wr * 64 + mf * 16 + lr;
        const int ca = ((kk >> 3) + lk) ^ (ra & 7);  // swizzled read chunk
        af[mf] = *reinterpret_cast<const bf16x8*>(&As[buf][ra * 64 + ca * 8]);
      }
#pragma unroll
      for (int nf = 0; nf < 2; nf++) {
        const int rb = wc * 32 + nf * 16 + lr;
        const int cb = ((kk >> 3) + lk) ^ (rb & 7);
        bfr[nf] = *reinterpret_cast<const bf16x8*>(&Bs[buf][rb * 64 + cb * 8]);
      }
#pragma unroll
      for (int mf = 0; mf < 4; mf++)
#pragma unroll
        for (int nf = 0; nf < 2; nf++)
          acc[mf][nf] = __builtin_amdgcn_mfma_f32_16x16x32_bf16(
              af[mf], bfr[nf], acc[mf][nf], 0, 0, 0);
    }
  };

  // T4 counted-vmcnt pipeline: 2 tiles staged ahead, never vmcnt(0) mid-loop
  stage(0);
  stage(1);
#pragma unroll
  for (int kt = 0; kt < 16; kt++) {
    if (kt < 15) {
      asm volatile("s_waitcnt vmcnt(6)" ::: "memory");
    } else {
      asm volatile("s_waitcnt vmcnt(0)" ::: "memory");
    }
    __builtin_amdgcn_sched_barrier(0);
    __builtin_amdgcn_s_barrier();  // tile kt ready for all waves
    __builtin_amdgcn_s_setprio(1);
    compute(kt & 1);
    __builtin_amdgcn_s_setprio(0);
    __builtin_amdgcn_s_barrier();  // all waves done reading buf[kt&1]
    if (kt < 14) stage(kt & 1);    // tile kt+2 overwrites buf[kt&1]
  }

  // epilogue: C/D layout col=lane&15, row=(lane>>4)*4+reg [m89]
  const int mlim = m_count - m0;
#pragma unroll
  for (int nf = 0; nf < 2; nf++) {
    const int c = n0 + wc * 32 + nf * 16 + lr;
    const float bval = bias[(e << 10) + c];
#pragma unroll
    for (int mf = 0; mf < 4; mf++) {
#pragma unroll
      for (int j = 0; j < 4; j++) {
        const int lrow2 = wr * 64 + mf * 16 + lk * 4 + j;
        if (lrow2 < mlim) {
          float v = acc[mf][nf][j] + bval;
          if (MODE == 0) {
            v = v > 0.f ? v : 0.f;
            hb[(size_t)(g0 + m0 + lrow2) * 1024 + c] = f32_to_bf16_bits(v);
          } else {
            int token = perm[g0 + m0 + lrow2];
            out[(size_t)token * 1024 + c] = v;
          }
        }
      }
    }
  }
}

// ---------- launch ----------
extern "C" void kernel_launch(void* const* d_in, const int* in_sizes, int n_in,
                              void* d_out, int out_size, void* d_ws, size_t ws_size,
                              hipStream_t stream) {
  const float* x = (const float*)d_in[0];
  const float* Wp = (const float*)d_in[1];
  const float* bp = (const float*)d_in[2];
  const float* W1 = (const float*)d_in[3];
  const float* b1 = (const float*)d_in[4];
  const float* W2 = (const float*)d_in[5];
  const float* b2 = (const float*)d_in[6];

  float* out = (float*)d_out;                      // [8192][1024]
  float* probs = out + (size_t)N_TOK * D_DIM;      // [8192][8]
  float* chosenF = probs + (size_t)N_TOK * E_NUM;  // [8192]

  char* ws = (char*)d_ws;
  int* chosen = (int*)(ws + 0);       // 32 KB
  int* perm = (int*)(ws + 32768);     // 32 KB
  float* WpT = (float*)(ws + 65536);  // 32 KB
  int* offsets = (int*)(ws + 98304);  // 64 B
  const size_t MB16 = 16777216;
  unsigned short* xb = (unsigned short*)(ws + 131072);          // 16 MB
  unsigned short* Wt1 = (unsigned short*)(ws + 131072 + MB16);  // 16 MB
  // overlap path: Wt2 separate (GEMM1 reads Wt1 while W2T is written);
  // sequential fallback: Wt2 aliases Wt1 (written after GEMM1 completes).
  const bool overlap = ws_size >= 131072 + 4 * MB16;
  unsigned short* Wt2 = (unsigned short*)(ws + 131072 + (overlap ? 2 : 1) * MB16);
  unsigned short* hb = (unsigned short*)(ws + 131072 + (overlap ? 3 : 2) * MB16);

  const int GEMM_BLOCKS = E_NUM * 64 * 16;  // 8192: worst-case m coverage x 16 n-tiles

  wpt_kernel<<<32, 256, 0, stream>>>(Wp, WpT);
  routing_w1t_kernel<<<4096, 256, 0, stream>>>(x, WpT, bp, probs, chosenF, chosen,
                                               xb, W1, Wt1);
  scan_scatter_kernel<<<E_NUM, 256, 0, stream>>>(chosen, offsets, perm);
  if (overlap) {
    moe_gemm_kernel<0><<<GEMM_BLOCKS + 2048, 256, 0, stream>>>(
        xb, Wt1, b1, offsets, perm, hb, nullptr, W2, Wt2, GEMM_BLOCKS);
  } else {
    moe_gemm_kernel<0><<<GEMM_BLOCKS, 256, 0, stream>>>(
        xb, Wt1, b1, offsets, perm, hb, nullptr, nullptr, nullptr, GEMM_BLOCKS);
    transpose_cast_kernel<<<dim3(16, 16, 8), 256, 0, stream>>>(W2, Wt2);
  }
  moe_gemm_kernel<1><<<GEMM_BLOCKS, 256, 0, stream>>>(
      hb, Wt2, b2, offsets, perm, nullptr, out, nullptr, nullptr, GEMM_BLOCKS);
}

// Round 14
// 117.562 us; speedup vs baseline: 1.2713x; 1.0730x over previous
//
#include <hip/hip_runtime.h>
#include <stdint.h>

#define N_TOK 8192
#define D_DIM 1024
#define E_NUM 8

typedef float f32x4 __attribute__((ext_vector_type(4)));
typedef __bf16 bf16x8 __attribute__((ext_vector_type(8)));

__device__ __forceinline__ unsigned short f32_to_bf16_bits(float f) {
  union { float f; uint32_t u; } v; v.f = f;
  uint32_t u = v.u;
  uint32_t r = u + 0x7fffu + ((u >> 16) & 1u);  // RNE
  return (unsigned short)(r >> 16);
}

__device__ __forceinline__ void load_lds16(const void* g, void* l) {
  // async global->LDS, 16B/lane, dest = uniform base + lane*16
  __builtin_amdgcn_global_load_lds(
      (const __attribute__((address_space(1))) void*)g,
      (__attribute__((address_space(3))) void*)l, 16, 0, 0);
}

// ---------- shared 64x64 fp32->bf16 transpose tile (LDS-staged) ----------
__device__ __forceinline__ void transpose_tile(unsigned short (*T)[72],
                                               const float* __restrict__ S,
                                               unsigned short* __restrict__ O,
                                               int r0, int c0, int t) {
  const int rr = t >> 4;
  const int cc = (t & 15) * 4;
#pragma unroll
  for (int p = 0; p < 4; p++) {
    int r = p * 16 + rr;
    float4 v = *reinterpret_cast<const float4*>(S + (size_t)(r0 + r) * 1024 + c0 + cc);
    T[cc + 0][r] = f32_to_bf16_bits(v.x);
    T[cc + 1][r] = f32_to_bf16_bits(v.y);
    T[cc + 2][r] = f32_to_bf16_bits(v.z);
    T[cc + 3][r] = f32_to_bf16_bits(v.w);
  }
  __syncthreads();
#pragma unroll
  for (int p = 0; p < 4; p++) {
    int c = p * 16 + rr;
    ushort4 o = *reinterpret_cast<const ushort4*>(&T[c][cc]);
    *reinterpret_cast<ushort4*>(O + (size_t)(c0 + c) * 1024 + r0 + cc) = o;
  }
}

// ---------- Wp [1024][8] -> WpT [8][1024] ----------
__global__ __launch_bounds__(256) void wpt_kernel(const float* __restrict__ Wp,
                                                  float* __restrict__ WpT) {
  int i = blockIdx.x * 256 + threadIdx.x;  // 8192 total
  int e = i >> 10, d = i & 1023;
  WpT[i] = Wp[(size_t)d * E_NUM + e];
}

// ---------- fused: routing (fp64 logits) + x->bf16 + W1 transpose ----------
// bids 0..2047: routing, 4 tokens/block. bids 2048..4095: W1 64x64 transpose tiles.
// fp64 logits so argmax matches the np reference exactly.
// NO global atomics (R3: 8192 same-line atomicAdds serialized ~70us of tail).
// Dispatch is ~90% of achieved HBM BW (~96MB moved) -- memory-bound.
__global__ __launch_bounds__(256) void routing_w1t_kernel(
    const float* __restrict__ x, const float* __restrict__ WpT,
    const float* __restrict__ bp, float* __restrict__ probs_out,
    float* __restrict__ chosenF, int* __restrict__ chosen,
    unsigned short* __restrict__ xb,
    const float* __restrict__ W1, unsigned short* __restrict__ W1t) {
  __shared__ __align__(16) unsigned short T[64][72];
  __shared__ __align__(16) float pbuf[4][8];
  if (blockIdx.x >= 2048) {  // transpose role
    const int tb = blockIdx.x - 2048;
    const int e = tb >> 8, rc = tb & 255;
    transpose_tile(T, W1 + ((size_t)e << 20), W1t + ((size_t)e << 20),
                   (rc >> 4) * 64, (rc & 15) * 64, threadIdx.x);
    return;
  }
  const int wave = threadIdx.x >> 6;
  const int lane = threadIdx.x & 63;
  const int token = blockIdx.x * 4 + wave;
  const float* xr = x + (size_t)token * D_DIM;
  unsigned short* xbr = xb + (size_t)token * D_DIM;
  double acc[E_NUM];
#pragma unroll
  for (int e = 0; e < E_NUM; e++) acc[e] = 0.0;
#pragma unroll
  for (int it = 0; it < 4; it++) {
    const int d0 = it * 256 + lane * 4;
    float4 xv = *reinterpret_cast<const float4*>(xr + d0);
    ushort4 o;
    o.x = f32_to_bf16_bits(xv.x);
    o.y = f32_to_bf16_bits(xv.y);
    o.z = f32_to_bf16_bits(xv.z);
    o.w = f32_to_bf16_bits(xv.w);
    *reinterpret_cast<ushort4*>(xbr + d0) = o;
#pragma unroll
    for (int e = 0; e < E_NUM; e++) {
      float4 w = *reinterpret_cast<const float4*>(WpT + (e << 10) + d0);  // coalesced
      acc[e] += (double)xv.x * (double)w.x;
      acc[e] += (double)xv.y * (double)w.y;
      acc[e] += (double)xv.z * (double)w.z;
      acc[e] += (double)xv.w * (double)w.w;
    }
  }
#pragma unroll
  for (int e = 0; e < E_NUM; e++) {
#pragma unroll
    for (int off = 32; off > 0; off >>= 1) acc[e] += __shfl_xor(acc[e], off);
  }
  if (lane == 0) {
    double lg[E_NUM];
#pragma unroll
    for (int e = 0; e < E_NUM; e++) lg[e] = acc[e] + (double)bp[e];
    int best = 0;
    double bv = lg[0];
#pragma unroll
    for (int e = 1; e < E_NUM; e++)
      if (lg[e] > bv) { bv = lg[e]; best = e; }  // strict > == first-max (jnp.argmax)
    double s = 0.0, ex[E_NUM];
#pragma unroll
    for (int e = 0; e < E_NUM; e++) { ex[e] = exp(lg[e] - bv); s += ex[e]; }
    double inv = 1.0 / s;
#pragma unroll
    for (int e = 0; e < E_NUM; e++) pbuf[wave][e] = (float)(ex[e] * inv);
    chosenF[token] = (float)best;
    chosen[token] = best;
  }
  __syncthreads();
  if (threadIdx.x < 8) {  // coalesced 128B probs store per block
    float4 v = *reinterpret_cast<const float4*>(
        &pbuf[threadIdx.x >> 1][(threadIdx.x & 1) * 4]);
    reinterpret_cast<float4*>(probs_out + (size_t)blockIdx.x * 32)[threadIdx.x] = v;
  }
}

// ---------- histogram + scan + scatter, ONE block, LDS atomics only ----------
// R14: reverted to the R7 single-block form. The R10 8-block variant cost
// ~6-7us (R13 vs R7 isolation): 8x redundant 32KB histogram scans + divergent
// per-expert scatter is slower than one 1024-thread block (~3us).
__global__ __launch_bounds__(1024) void scan_scatter_kernel(
    const int* __restrict__ chosen, int* __restrict__ offsets,
    int* __restrict__ perm) {
  __shared__ int hist[E_NUM];
  __shared__ int curs[E_NUM];
  const int t = threadIdx.x;
  if (t < E_NUM) hist[t] = 0;
  __syncthreads();
  for (int n = t; n < N_TOK; n += 1024) atomicAdd(&hist[chosen[n]], 1);
  __syncthreads();
  if (t == 0) {
    int off = 0;
    for (int e = 0; e < E_NUM; e++) { offsets[e] = off; curs[e] = off; off += hist[e]; }
    offsets[E_NUM] = off;
  }
  __syncthreads();
  for (int n = t; n < N_TOK; n += 1024) {
    int e = chosen[n];
    int p = atomicAdd(&curs[e], 1);  // in-group order irrelevant
    perm[p] = n;
  }
}

// ---------- standalone per-expert transpose (sequential fallback path) ----------
__global__ __launch_bounds__(256) void transpose_cast_kernel(
    const float* __restrict__ src, unsigned short* __restrict__ dst) {
  __shared__ __align__(16) unsigned short T[64][72];
  const int e = blockIdx.z;
  transpose_tile(T, src + ((size_t)e << 20), dst + ((size_t)e << 20),
                 blockIdx.y * 64, blockIdx.x * 64, threadIdx.x);
}

// ---------- grouped GEMM: 128x64 tile, BK=64, 4 waves — R7-EXACT (measured opt) ----
// Full search results (R4-R12, same-run-comparable): counted-vmcnt 128x64
// (this) = 47us; every other {shape, schedule, depth, occupancy} variant =
// 49-63us. Per-pipe busy at 47us: MFMA ~6us, LDS-issue ~15us, VALU ~5us,
// HBM 20% -> plateau is the lockstep ds_read->MFMA chain; only an m201-style
// 8-phase fine interleave might break it (high risk, m152/m232).
// Schedule: prologue stage(t0,t1); steady {vmcnt(6); barrier; setprio(1);
// MFMA; setprio(0); barrier; stage(t+2)} -- never vmcnt(0) mid-loop.
// T2 swizzle per rule #21: linear LDS dest, source chunk ^= lrow, read
// chunk ^= row&7. bids >= gemm_blocks: W2 transpose ride-along (GEMM1 only).
// MODE 0: h = relu(x[perm] @ W1t^T + b1) -> hb   MODE 1: out[perm] = hb @ W2t^T + b2
template <int MODE>
__global__ __launch_bounds__(256) void moe_gemm_kernel(
    const unsigned short* __restrict__ Abase,  // xb (MODE0) / hb (MODE1)
    const unsigned short* __restrict__ Wt,     // bf16 [E][1024(n)][1024(k)]
    const float* __restrict__ bias,            // [E][1024]
    const int* __restrict__ offsets, const int* __restrict__ perm,
    unsigned short* __restrict__ hb, float* __restrict__ out,
    const float* __restrict__ tsrc, unsigned short* __restrict__ tdst,
    int gemm_blocks) {
  __shared__ __align__(16) unsigned short As[2][128 * 64];  // 32 KB
  __shared__ __align__(16) unsigned short Bs[2][64 * 64];   // 16 KB

  if ((int)blockIdx.x >= gemm_blocks) {  // transpose role (MODE 0 overlap path)
    const int tb = blockIdx.x - gemm_blocks;
    const int e = tb >> 8, rc = tb & 255;
    auto T = reinterpret_cast<unsigned short(*)[72]>(&As[0][0]);
    transpose_tile(T, tsrc + ((size_t)e << 20), tdst + ((size_t)e << 20),
                   (rc >> 4) * 64, (rc & 15) * 64, threadIdx.x);
    return;
  }

  const int e = blockIdx.x & 7;
  const int slot = blockIdx.x >> 3;   // 0..1023 per expert
  const int g0 = offsets[e];
  const int m_count = offsets[e + 1] - g0;
  const int m0 = (slot >> 4) * 128;   // 64 m-tiles: covers any routing skew
  if (m0 >= m_count) return;          // uniform early-exit, before any barrier
  const int n0 = (slot & 15) * 64;

  const int tid = threadIdx.x;
  const int wid = tid >> 6, lane = tid & 63;
  const int lrow = lane >> 3;        // 0..7: row within the wave's 8-row stripe
  const int lchunk = lane & 7;       // 16B chunk within the 128B k-row
  const int schunk = lchunk ^ lrow;  // pre-swizzled source chunk (involution)

  const unsigned short* ga[4];
  const unsigned short* gb[2];
  int abase[4], bbase[2];
  const unsigned short* WtE = Wt + ((size_t)e << 20);
#pragma unroll
  for (int t = 0; t < 4; t++) {
    const int rbase = t * 32 + wid * 8;  // wave-uniform, multiple of 8
    const int r = rbase + lrow;          // 0..127
    int gr = g0 + m0 + r;
    if (gr > N_TOK - 1) gr = N_TOK - 1;  // clamp partial m-tiles
    const int arow = (MODE == 0) ? perm[gr] : gr;
    ga[t] = Abase + (size_t)arow * 1024 + schunk * 8;
    abase[t] = rbase * 64;  // linear LDS dest, wave-uniform (required)
  }
#pragma unroll
  for (int t = 0; t < 2; t++) {
    const int rbase = t * 32 + wid * 8;
    const int r = rbase + lrow;  // 0..63
    gb[t] = WtE + (size_t)(n0 + r) * 1024 + schunk * 8;
    bbase[t] = rbase * 64;
  }

  f32x4 acc[4][2];
  const f32x4 zero4 = {0.f, 0.f, 0.f, 0.f};
#pragma unroll
  for (int i = 0; i < 4; i++)
#pragma unroll
    for (int j = 0; j < 2; j++) acc[i][j] = zero4;

  const int wr = wid >> 1, wc = wid & 1;  // wave tile: 64 rows x 32 cols
  const int lr = lane & 15, lk = lane >> 4;

  auto stage = [&](int buf) {
#pragma unroll
    for (int t = 0; t < 4; t++) {
      load_lds16(ga[t], &As[buf][abase[t]]);
      ga[t] += 64;
    }
#pragma unroll
    for (int t = 0; t < 2; t++) {
      load_lds16(gb[t], &Bs[buf][bbase[t]]);
      gb[t] += 64;
    }
  };
  auto compute = [&](int buf) {
#pragma unroll
    for (int kk = 0; kk < 64; kk += 32) {
      bf16x8 af[4], bfr[2];
#pragma unroll
      for (int mf = 0; mf < 4; mf++) {
        const int ra = wr * 64 + mf * 16 + lr;
        const int ca = ((kk >> 3) + lk) ^ (ra & 7);  // swizzled read chunk
        af[mf] = *reinterpret_cast<const bf16x8*>(&As[buf][ra * 64 + ca * 8]);
      }
#pragma unroll
      for (int nf = 0; nf < 2; nf++) {
        const int rb = wc * 32 + nf * 16 + lr;
        const int cb = ((kk >> 3) + lk) ^ (rb & 7);
        bfr[nf] = *reinterpret_cast<const bf16x8*>(&Bs[buf][rb * 64 + cb * 8]);
      }
#pragma unroll
      for (int mf = 0; mf < 4; mf++)
#pragma unroll
        for (int nf = 0; nf < 2; nf++)
          acc[mf][nf] = __builtin_amdgcn_mfma_f32_16x16x32_bf16(
              af[mf], bfr[nf], acc[mf][nf], 0, 0, 0);
    }
  };

  // T4 counted-vmcnt pipeline: 2 tiles staged ahead, never vmcnt(0) mid-loop
  stage(0);
  stage(1);
#pragma unroll
  for (int kt = 0; kt < 16; kt++) {
    if (kt < 15) {
      asm volatile("s_waitcnt vmcnt(6)" ::: "memory");
    } else {
      asm volatile("s_waitcnt vmcnt(0)" ::: "memory");
    }
    __builtin_amdgcn_sched_barrier(0);
    __builtin_amdgcn_s_barrier();  // tile kt ready for all waves
    __builtin_amdgcn_s_setprio(1);
    compute(kt & 1);
    __builtin_amdgcn_s_setprio(0);
    __builtin_amdgcn_s_barrier();  // all waves done reading buf[kt&1]
    if (kt < 14) stage(kt & 1);    // tile kt+2 overwrites buf[kt&1]
  }

  // epilogue: C/D layout col=lane&15, row=(lane>>4)*4+reg [m89]
  const int mlim = m_count - m0;
#pragma unroll
  for (int nf = 0; nf < 2; nf++) {
    const int c = n0 + wc * 32 + nf * 16 + lr;
    const float bval = bias[(e << 10) + c];
#pragma unroll
    for (int mf = 0; mf < 4; mf++) {
#pragma unroll
      for (int j = 0; j < 4; j++) {
        const int lrow2 = wr * 64 + mf * 16 + lk * 4 + j;
        if (lrow2 < mlim) {
          float v = acc[mf][nf][j] + bval;
          if (MODE == 0) {
            v = v > 0.f ? v : 0.f;
            hb[(size_t)(g0 + m0 + lrow2) * 1024 + c] = f32_to_bf16_bits(v);
          } else {
            int token = perm[g0 + m0 + lrow2];
            out[(size_t)token * 1024 + c] = v;
          }
        }
      }
    }
  }
}

// ---------- launch ----------
extern "C" void kernel_launch(void* const* d_in, const int* in_sizes, int n_in,
                              void* d_out, int out_size, void* d_ws, size_t ws_size,
                              hipStream_t stream) {
  const float* x = (const float*)d_in[0];
  const float* Wp = (const float*)d_in[1];
  const float* bp = (const float*)d_in[2];
  const float* W1 = (const float*)d_in[3];
  const float* b1 = (const float*)d_in[4];
  const float* W2 = (const float*)d_in[5];
  const float* b2 = (const float*)d_in[6];

  float* out = (float*)d_out;                      // [8192][1024]
  float* probs = out + (size_t)N_TOK * D_DIM;      // [8192][8]
  float* chosenF = probs + (size_t)N_TOK * E_NUM;  // [8192]

  char* ws = (char*)d_ws;
  int* chosen = (int*)(ws + 0);       // 32 KB
  int* perm = (int*)(ws + 32768);     // 32 KB
  float* WpT = (float*)(ws + 65536);  // 32 KB
  int* offsets = (int*)(ws + 98304);  // 64 B
  const size_t MB16 = 16777216;
  unsigned short* xb = (unsigned short*)(ws + 131072);          // 16 MB
  unsigned short* Wt1 = (unsigned short*)(ws + 131072 + MB16);  // 16 MB
  // overlap path: Wt2 separate (GEMM1 reads Wt1 while W2T is written);
  // sequential fallback: Wt2 aliases Wt1 (written after GEMM1 completes).
  const bool overlap = ws_size >= 131072 + 4 * MB16;
  unsigned short* Wt2 = (unsigned short*)(ws + 131072 + (overlap ? 2 : 1) * MB16);
  unsigned short* hb = (unsigned short*)(ws + 131072 + (overlap ? 3 : 2) * MB16);

  const int GEMM_BLOCKS = E_NUM * 64 * 16;  // 8192: worst-case m coverage x 16 n-tiles

  wpt_kernel<<<32, 256, 0, stream>>>(Wp, WpT);
  routing_w1t_kernel<<<4096, 256, 0, stream>>>(x, WpT, bp, probs, chosenF, chosen,
                                               xb, W1, Wt1);
  scan_scatter_kernel<<<1, 1024, 0, stream>>>(chosen, offsets, perm);
  if (overlap) {
    moe_gemm_kernel<0><<<GEMM_BLOCKS + 2048, 256, 0, stream>>>(
        xb, Wt1, b1, offsets, perm, hb, nullptr, W2, Wt2, GEMM_BLOCKS);
  } else {
    moe_gemm_kernel<0><<<GEMM_BLOCKS, 256, 0, stream>>>(
        xb, Wt1, b1, offsets, perm, hb, nullptr, nullptr, nullptr, GEMM_BLOCKS);
    transpose_cast_kernel<<<dim3(16, 16, 8), 256, 0, stream>>>(W2, Wt2);
  }
  moe_gemm_kernel<1><<<GEMM_BLOCKS, 256, 0, stream>>>(
      hb, Wt2, b2, offsets, perm, nullptr, out, nullptr, nullptr, GEMM_BLOCKS);
}